// Round 1
// baseline (738.493 us; speedup 1.0000x reference)
//
#include <hip/hip_runtime.h>

#define NPTS 65536
#define INC  256
#define MID  64
#define KNB  16

typedef __attribute__((ext_vector_type(8))) short short8;
typedef __attribute__((ext_vector_type(4))) float f32x4;

#define MFMA(a, b, c) __builtin_amdgcn_mfma_f32_16x16x32_bf16((a), (b), (c), 0, 0, 0)

// float -> bf16 (RNE, no NaN handling needed here)
__device__ inline short f2bf(float f) {
    unsigned int u = __builtin_bit_cast(unsigned int, f);
    unsigned int r = (u + 0x7fffu + ((u >> 16) & 1u)) >> 16;
    return (short)r;
}
__device__ inline float bf2f(short s) {
    unsigned int u = ((unsigned int)(unsigned short)s) << 16;
    return __builtin_bit_cast(float, u);
}
__device__ inline short8 cvtf8(f32x4 a, f32x4 b) {
    short8 r;
    r[0] = f2bf(a[0]); r[1] = f2bf(a[1]); r[2] = f2bf(a[2]); r[3] = f2bf(a[3]);
    r[4] = f2bf(b[0]); r[5] = f2bf(b[1]); r[6] = f2bf(b[2]); r[7] = f2bf(b[3]);
    return r;
}
__device__ inline short8 load_cvt8(const float* __restrict__ p) {
    const f32x4* v = (const f32x4*)p;
    f32x4 a = v[0], b = v[1];
    return cvtf8(a, b);
}

// ---------------------------------------------------------------------------
// Kernel 1: xx = feats @ w_in.T ; q/k/v = xx @ w_{q,k,v}.T + b
// one wave = 16 rows; block = 4 waves = 64 rows; grid = 1024
// q stored fp32, k/v stored bf16 (gathered in kernel 2)
// ---------------------------------------------------------------------------
__global__ __launch_bounds__(256) void k_qkv(
    const float* __restrict__ feats, const float* __restrict__ w_in,
    const float* __restrict__ w_q, const float* __restrict__ b_q,
    const float* __restrict__ w_k, const float* __restrict__ b_k,
    const float* __restrict__ w_v, const float* __restrict__ b_v,
    float* __restrict__ q_out, short* __restrict__ k_out, short* __restrict__ v_out)
{
    __shared__ __align__(16) short XL[4][16 * MID];   // xx tile, bf16, per wave
    const int wave = threadIdx.x >> 6, lane = threadIdx.x & 63;
    const int l15 = lane & 15, quad = lane >> 4;
    const int rb = (blockIdx.x * 4 + wave) * 16;

    f32x4 acc[4];
    #pragma unroll
    for (int nt = 0; nt < 4; nt++) acc[nt] = (f32x4){0.f, 0.f, 0.f, 0.f};

    const float* arow = feats + (size_t)(rb + l15) * INC + quad * 8;
    #pragma unroll
    for (int ks = 0; ks < 8; ks++) {
        short8 a = load_cvt8(arow + ks * 32);
        #pragma unroll
        for (int nt = 0; nt < 4; nt++) {
            short8 b = load_cvt8(w_in + (size_t)(nt * 16 + l15) * INC + ks * 32 + quad * 8);
            acc[nt] = MFMA(a, b, acc[nt]);
        }
    }
    // xx (D layout) -> LDS bf16 in [row][chan] order
    #pragma unroll
    for (int nt = 0; nt < 4; nt++)
        #pragma unroll
        for (int r = 0; r < 4; r++)
            XL[wave][(quad * 4 + r) * MID + nt * 16 + l15] = f2bf(acc[nt][r]);

    // A frags for the 64x64 GEMMs (same-wave LDS RAW; compiler inserts waits)
    short8 a0 = *(const short8*)&XL[wave][l15 * MID + quad * 8];
    short8 a1 = *(const short8*)&XL[wave][l15 * MID + 32 + quad * 8];

    // Q (fp32 out)
    #pragma unroll
    for (int nt = 0; nt < 4; nt++) {
        short8 b0 = load_cvt8(w_q + (size_t)(nt * 16 + l15) * MID + quad * 8);
        short8 b1 = load_cvt8(w_q + (size_t)(nt * 16 + l15) * MID + 32 + quad * 8);
        f32x4 c = (f32x4){0.f, 0.f, 0.f, 0.f};
        c = MFMA(a0, b0, c); c = MFMA(a1, b1, c);
        float bias = b_q[nt * 16 + l15];
        #pragma unroll
        for (int r = 0; r < 4; r++)
            q_out[(size_t)(rb + quad * 4 + r) * MID + nt * 16 + l15] = c[r] + bias;
    }
    // K (bf16 out)
    #pragma unroll
    for (int nt = 0; nt < 4; nt++) {
        short8 b0 = load_cvt8(w_k + (size_t)(nt * 16 + l15) * MID + quad * 8);
        short8 b1 = load_cvt8(w_k + (size_t)(nt * 16 + l15) * MID + 32 + quad * 8);
        f32x4 c = (f32x4){0.f, 0.f, 0.f, 0.f};
        c = MFMA(a0, b0, c); c = MFMA(a1, b1, c);
        float bias = b_k[nt * 16 + l15];
        #pragma unroll
        for (int r = 0; r < 4; r++)
            k_out[(size_t)(rb + quad * 4 + r) * MID + nt * 16 + l15] = f2bf(c[r] + bias);
    }
    // V (bf16 out)
    #pragma unroll
    for (int nt = 0; nt < 4; nt++) {
        short8 b0 = load_cvt8(w_v + (size_t)(nt * 16 + l15) * MID + quad * 8);
        short8 b1 = load_cvt8(w_v + (size_t)(nt * 16 + l15) * MID + 32 + quad * 8);
        f32x4 c = (f32x4){0.f, 0.f, 0.f, 0.f};
        c = MFMA(a0, b0, c); c = MFMA(a1, b1, c);
        float bias = b_v[nt * 16 + l15];
        #pragma unroll
        for (int r = 0; r < 4; r++)
            v_out[(size_t)(rb + quad * 4 + r) * MID + nt * 16 + l15] = f2bf(c[r] + bias);
    }
}

// ---------------------------------------------------------------------------
// Kernel 2: per-point attention. one wave = one point; block = 4 points.
// ---------------------------------------------------------------------------
__global__ __launch_bounds__(256) void k_attn(
    const float* __restrict__ pos, const int* __restrict__ idx,
    const float* __restrict__ q_ws, const short* __restrict__ k_bf, const short* __restrict__ v_bf,
    const float* __restrict__ pe_w1, const float* __restrict__ pe_b1,
    const float* __restrict__ pe_g1, const float* __restrict__ pe_be1,
    const float* __restrict__ pe_m1, const float* __restrict__ pe_v1,
    const float* __restrict__ pe_w2, const float* __restrict__ pe_b2,
    const float* __restrict__ pe_g2, const float* __restrict__ pe_be2,
    const float* __restrict__ pe_m2, const float* __restrict__ pe_v2,
    const float* __restrict__ ga_w1, const float* __restrict__ ga_b1,
    const float* __restrict__ ga_g1, const float* __restrict__ ga_be1,
    const float* __restrict__ ga_m1, const float* __restrict__ ga_v1,
    const float* __restrict__ ga_w2, const float* __restrict__ ga_b2,
    const float* __restrict__ ga_g2, const float* __restrict__ ga_be2,
    const float* __restrict__ ga_m2, const float* __restrict__ ga_v2,
    short* __restrict__ om_bf)
{
    __shared__ __align__(16) short Wb[4][16 * MID];   // bf16 activation tile (A frags)
    __shared__ float Sb[4][16 * 65];                  // softmax weights, padded rows
    __shared__ float PS[4][16 * 4];                   // pos_enc layer-1 output per neighbor
    __shared__ int   JI[4][16];

    const int wave = threadIdx.x >> 6, lane = threadIdx.x & 63;
    const int l15 = lane & 15, quad = lane >> 4;
    const int n = blockIdx.x * 4 + wave;

    // stage neighbor indices + pos_enc layer 1 (3ch) per neighbor
    if (lane < 16) {
        int m = idx[n * KNB + lane];
        JI[wave][lane] = m;
        float px = pos[(size_t)m * 3 + 0];
        float py = pos[(size_t)m * 3 + 1];
        float pz = pos[(size_t)m * 3 + 2];
        #pragma unroll
        for (int c = 0; c < 3; c++) {
            float s  = pe_g1[c] * rsqrtf(pe_v1[c] + 1e-5f);
            float sh = (pe_b1[c] - pe_m1[c]) * s + pe_be1[c];
            float d  = px * pe_w1[c * 3 + 0] + py * pe_w1[c * 3 + 1] + pz * pe_w1[c * 3 + 2];
            PS[wave][lane * 4 + c] = fmaxf(d * s + sh, 0.f);
        }
    }

    // lane = channel params for pos_enc layer 2
    float w20 = pe_w2[lane * 3 + 0], w21 = pe_w2[lane * 3 + 1], w22 = pe_w2[lane * 3 + 2];
    float s2  = pe_g2[lane] * rsqrtf(pe_v2[lane] + 1e-5f);
    float sh2 = (pe_b2[lane] - pe_m2[lane]) * s2 + pe_be2[lane];
    float qv  = q_ws[(size_t)n * MID + lane];

    // D-layout folded BN params for mlp_gamma (channel o = nt*16 + l15)
    float gs1[4], gh1[4], gs2[4], gh2[4];
    #pragma unroll
    for (int nt = 0; nt < 4; nt++) {
        int o = nt * 16 + l15;
        gs1[nt] = ga_g1[o] * rsqrtf(ga_v1[o] + 1e-5f);
        gh1[nt] = (ga_b1[o] - ga_m1[o]) * gs1[nt] + ga_be1[o];
        gs2[nt] = ga_g2[o] * rsqrtf(ga_v2[o] + 1e-5f);
        gh2[nt] = (ga_b2[o] - ga_m2[o]) * gs2[nt] + ga_be2[o];
    }

    // register-resident B fragments for both mlp_gamma layers
    short8 B1[2][4], B2[2][4];
    #pragma unroll
    for (int ks = 0; ks < 2; ks++)
        #pragma unroll
        for (int nt = 0; nt < 4; nt++) {
            B1[ks][nt] = load_cvt8(ga_w1 + (size_t)(nt * 16 + l15) * MID + ks * 32 + quad * 8);
            B2[ks][nt] = load_cvt8(ga_w2 + (size_t)(nt * 16 + l15) * MID + ks * 32 + quad * 8);
        }

    __syncthreads();

    // gather + pos_enc layer 2 + build w = xk - q + p  (lane = channel)
    float xvp[KNB];
    #pragma unroll
    for (int j = 0; j < KNB; j++) {
        int m = JI[wave][j];
        float kg = bf2f(k_bf[(size_t)m * MID + lane]);
        float vg = bf2f(v_bf[(size_t)m * MID + lane]);
        float p10 = PS[wave][j * 4 + 0], p11 = PS[wave][j * 4 + 1], p12 = PS[wave][j * 4 + 2];
        float d = p10 * w20 + p11 * w21 + p12 * w22;
        float p = fmaxf(d * s2 + sh2, 0.f);
        Wb[wave][j * MID + lane] = f2bf(kg - qv + p);
        xvp[j] = vg + p;
    }

    // mlp_gamma layer 1
    short8 a0 = *(const short8*)&Wb[wave][l15 * MID + quad * 8];
    short8 a1 = *(const short8*)&Wb[wave][l15 * MID + 32 + quad * 8];
    #pragma unroll
    for (int nt = 0; nt < 4; nt++) {
        f32x4 c = (f32x4){0.f, 0.f, 0.f, 0.f};
        c = MFMA(a0, B1[0][nt], c);
        c = MFMA(a1, B1[1][nt], c);
        #pragma unroll
        for (int r = 0; r < 4; r++) {
            float v = fmaxf(c[r] * gs1[nt] + gh1[nt], 0.f);
            Wb[wave][(quad * 4 + r) * MID + nt * 16 + l15] = f2bf(v);
        }
    }

    // mlp_gamma layer 2
    short8 c0 = *(const short8*)&Wb[wave][l15 * MID + quad * 8];
    short8 c1 = *(const short8*)&Wb[wave][l15 * MID + 32 + quad * 8];
    float sm[4][4];
    #pragma unroll
    for (int nt = 0; nt < 4; nt++) {
        f32x4 c = (f32x4){0.f, 0.f, 0.f, 0.f};
        c = MFMA(c0, B2[0][nt], c);
        c = MFMA(c1, B2[1][nt], c);
        #pragma unroll
        for (int r = 0; r < 4; r++)
            sm[nt][r] = fmaxf(c[r] * gs2[nt] + gh2[nt], 0.f);
    }

    // softmax over the 16 neighbors per channel (column = nt*16+l15)
    #pragma unroll
    for (int nt = 0; nt < 4; nt++) {
        float mx = fmaxf(fmaxf(sm[nt][0], sm[nt][1]), fmaxf(sm[nt][2], sm[nt][3]));
        mx = fmaxf(mx, __shfl_xor(mx, 16));
        mx = fmaxf(mx, __shfl_xor(mx, 32));
        float e[4], s = 0.f;
        #pragma unroll
        for (int r = 0; r < 4; r++) { e[r] = __expf(sm[nt][r] - mx); s += e[r]; }
        s += __shfl_xor(s, 16);
        s += __shfl_xor(s, 32);
        float inv = 1.0f / s;
        #pragma unroll
        for (int r = 0; r < 4; r++)
            Sb[wave][(quad * 4 + r) * 65 + nt * 16 + l15] = e[r] * inv;
    }

    // out_mid[n][lane] = sum_j (xv+p)[j][lane] * softmax_w[j][lane]
    float oacc = 0.f;
    #pragma unroll
    for (int j = 0; j < KNB; j++)
        oacc += xvp[j] * Sb[wave][j * 65 + lane];
    om_bf[(size_t)n * MID + lane] = f2bf(oacc);
}

// ---------------------------------------------------------------------------
// Kernel 3: out = out_mid @ w_out.T + feats   [N,64]@[64,256]
// one wave = 16 rows; block = 64 rows; grid = 1024
// ---------------------------------------------------------------------------
__global__ __launch_bounds__(256) void k_out(
    const short* __restrict__ om_bf, const float* __restrict__ w_out,
    const float* __restrict__ feats, float* __restrict__ out)
{
    const int wave = threadIdx.x >> 6, lane = threadIdx.x & 63;
    const int l15 = lane & 15, quad = lane >> 4;
    const int rb = (blockIdx.x * 4 + wave) * 16;

    short8 a0 = *(const short8*)(om_bf + (size_t)(rb + l15) * MID + quad * 8);
    short8 a1 = *(const short8*)(om_bf + (size_t)(rb + l15) * MID + 32 + quad * 8);

    #pragma unroll
    for (int nt = 0; nt < 16; nt++) {
        short8 b0 = load_cvt8(w_out + (size_t)(nt * 16 + l15) * MID + quad * 8);
        short8 b1 = load_cvt8(w_out + (size_t)(nt * 16 + l15) * MID + 32 + quad * 8);
        f32x4 c = (f32x4){0.f, 0.f, 0.f, 0.f};
        c = MFMA(a0, b0, c);
        c = MFMA(a1, b1, c);
        #pragma unroll
        for (int r = 0; r < 4; r++) {
            size_t off = (size_t)(rb + quad * 4 + r) * INC + nt * 16 + l15;
            out[off] = c[r] + feats[off];
        }
    }
}

extern "C" void kernel_launch(void* const* d_in, const int* in_sizes, int n_in,
                              void* d_out, int out_size, void* d_ws, size_t ws_size,
                              hipStream_t stream)
{
    const float* feats = (const float*)d_in[0];
    const float* pos   = (const float*)d_in[1];
    const int*   idx   = (const int*)d_in[2];
    const float* w_in  = (const float*)d_in[3];
    const float* w_q   = (const float*)d_in[4];
    const float* b_q   = (const float*)d_in[5];
    const float* w_k   = (const float*)d_in[6];
    const float* b_k   = (const float*)d_in[7];
    const float* w_v   = (const float*)d_in[8];
    const float* b_v   = (const float*)d_in[9];
    const float* pe_w1 = (const float*)d_in[10];
    const float* pe_b1 = (const float*)d_in[11];
    const float* pe_g1 = (const float*)d_in[12];
    const float* pe_be1= (const float*)d_in[13];
    const float* pe_m1 = (const float*)d_in[14];
    const float* pe_v1 = (const float*)d_in[15];
    const float* pe_w2 = (const float*)d_in[16];
    const float* pe_b2 = (const float*)d_in[17];
    const float* pe_g2 = (const float*)d_in[18];
    const float* pe_be2= (const float*)d_in[19];
    const float* pe_m2 = (const float*)d_in[20];
    const float* pe_v2 = (const float*)d_in[21];
    const float* ga_w1 = (const float*)d_in[22];
    const float* ga_b1 = (const float*)d_in[23];
    const float* ga_g1 = (const float*)d_in[24];
    const float* ga_be1= (const float*)d_in[25];
    const float* ga_m1 = (const float*)d_in[26];
    const float* ga_v1 = (const float*)d_in[27];
    const float* ga_w2 = (const float*)d_in[28];
    const float* ga_b2 = (const float*)d_in[29];
    const float* ga_g2 = (const float*)d_in[30];
    const float* ga_be2= (const float*)d_in[31];
    const float* ga_m2 = (const float*)d_in[32];
    const float* ga_v2 = (const float*)d_in[33];
    const float* w_out = (const float*)d_in[34];

    char* ws = (char*)d_ws;
    float* q_ws  = (float*)(ws);                           // 16 MB
    short* k_bf  = (short*)(ws + (size_t)16 * 1024 * 1024); // 8 MB
    short* v_bf  = (short*)(ws + (size_t)24 * 1024 * 1024); // 8 MB
    short* om_bf = (short*)(ws + (size_t)32 * 1024 * 1024); // 8 MB

    k_qkv<<<NPTS / 64, 256, 0, stream>>>(feats, w_in, w_q, b_q, w_k, b_k, w_v, b_v,
                                         q_ws, k_bf, v_bf);
    k_attn<<<NPTS / 4, 256, 0, stream>>>(pos, idx, q_ws, k_bf, v_bf,
                                         pe_w1, pe_b1, pe_g1, pe_be1, pe_m1, pe_v1,
                                         pe_w2, pe_b2, pe_g2, pe_be2, pe_m2, pe_v2,
                                         ga_w1, ga_b1, ga_g1, ga_be1, ga_m1, ga_v1,
                                         ga_w2, ga_b2, ga_g2, ga_be2, ga_m2, ga_v2,
                                         om_bf);
    k_out<<<NPTS / 64, 256, 0, stream>>>(om_bf, w_out, feats, (float*)d_out);
}